// Round 18
// baseline (64.144 us; speedup 1.0000x reference)
//
#include <hip/hip_runtime.h>
#include <hip/hip_bf16.h>

#define NN 8192
#define DK 256
#define NE 131072
#define T128 64                       // 128-row tiles per dim
#define NBLK (T128*(T128+1)/2)        // 2080 upper-triangular tile pairs
#define L2E 1.44269504f
#define SAT_L2 144.269504f            // 100/ln2 (x ln2 at block scale -> 100)
#define LN2D 0.6931471805599453

typedef __attribute__((ext_vector_type(8))) short bf16x8;
typedef __attribute__((ext_vector_type(4))) float f32x4;
typedef const __attribute__((address_space(1))) void* gas1_t;
typedef __attribute__((address_space(3))) void* las3_t;

// g_mask: BSS-zero at load; scatter sets bits, k_final's edge-cleanup
// (plain stores of 0) restores all-zero every call. No zeroing pass.
__device__ __align__(16) unsigned       g_mask[(size_t)NN*NN/32]; // 8 MB bitmask
__device__ __align__(16) unsigned short g_bf[(size_t)NN*DK];      // 4 MB bf16 copy
__device__ __align__(16) double g_part[NBLK];                     // per-block partials

__device__ __forceinline__ unsigned short f2bf(float f) {
    unsigned u = __float_as_uint(f);
    unsigned r = (u + 0x7FFFu + ((u >> 16) & 1u)) >> 16;   // RNE
    return (unsigned short)r;
}

// ---- Kernel 1: convert l_enc->bf16 AND scatter edges ----
__global__ void k_convscat(const float* __restrict__ x,
                           const long long* __restrict__ ei) {
    int i = blockIdx.x * 256 + threadIdx.x;          // 0 .. 524287
    float4 v = ((const float4*)x)[i];
    ushort4 b;
    b.x = f2bf(v.x); b.y = f2bf(v.y); b.z = f2bf(v.z); b.w = f2bf(v.w);
    *(ushort4*)(&g_bf[(size_t)i * 4]) = b;
    if (blockIdx.x < NE / 256) {                     // first 512 blocks: 256 edges each
        int e = blockIdx.x * 256 + threadIdx.x;
        int ii = (int)ei[e];
        int jj = (int)ei[NE + e];
        atomicOr(&g_mask[(size_t)ii * (NN/32) + (jj >> 5)], 1u << (jj & 31));
        atomicOr(&g_mask[(size_t)jj * (NN/32) + (ii >> 5)], 1u << (ii & 31));
    }
}

// ---- Kernel 2: dbuf issue-early pipeline + light waves ----
// R6's proven structure (STAGE(next buf) BEFORE compute, ONE barrier/stage:
// the vmcnt(0) drain waits on loads issued a full compute phase earlier,
// >= L2 latency) combined with R17's light-wave geometry (512 thr, 8 waves
// of 64x32, acc[4][2]=32 regs -> fits (512,4) 128-reg cap) => 2 blocks/CU
// = 16 waves/CU at 64 KB LDS. (R12's dbuf failure was BK=32: half the
// compute window + 2x barrier count. Here BK=64.)
__global__ __launch_bounds__(512, 4) void k_loss() {
    __shared__ __align__(16) unsigned short lsA[2][128 * 64];   // 2 x 16 KB
    __shared__ __align__(16) unsigned short lsB[2][128 * 64];   // 2 x 16 KB
    __shared__ double s_part[8];

    // XCD-aware swizzle (2080 = 8*260, bijective), then decode (ti,tj), ti<=tj
    int orig = blockIdx.x;
    int bid  = (orig & 7) * (NBLK / 8) + (orig >> 3);
    int rem = bid, ti = 0;
    while (rem >= T128 - ti) { rem -= T128 - ti; ++ti; }
    int tj = ti + rem;

    const int tid  = threadIdx.x;
    const int lane = tid & 63;
    const int w    = tid >> 6;       // wave 0..7
    const int wr   = w >> 2;         // row half 0..1  (64 rows)
    const int wc   = w & 3;          // col quarter 0..3 (32 cols)
    const int lr   = lane & 15;
    const int lq   = lane >> 4;      // 0..3

    // staging: chunk c = i*512+tid -> row r = i*64+(tid>>3), slot sq = tid&7;
    // LDS slot sq holds global chunk gq = sq ^ (r&7); r&7 = (tid>>3)&7 (i-inv).
    const int gq = (tid & 7) ^ ((tid >> 3) & 7);
    const unsigned short* srcA0 = g_bf + (size_t)(ti * 128 + (tid >> 3)) * DK + gq * 8;
    const size_t dB = (size_t)(tj - ti) * 128 * DK;   // B-panel offset (uniform)
    const int lds0 = tid * 8;                          // element offset, 16 B/lane

#define STAGE(b, kt) do {                                                          \
    _Pragma("unroll")                                                              \
    for (int i = 0; i < 2; ++i) {                                                  \
        __builtin_amdgcn_global_load_lds(                                          \
            (gas1_t)(const void*)(srcA0 + (size_t)i * 64 * DK + (kt) * 64),        \
            (las3_t)(void*)&lsA[b][lds0 + i * 4096], 16, 0, 0);                    \
        __builtin_amdgcn_global_load_lds(                                          \
            (gas1_t)(const void*)(srcA0 + dB + (size_t)i * 64 * DK + (kt) * 64),   \
            (las3_t)(void*)&lsB[b][lds0 + i * 4096], 16, 0, 0);                    \
    }                                                                              \
} while (0)

    f32x4 acc[4][2] = {};

    // prologue: stage kt=0 into buf 0
    STAGE(0, 0);
    __syncthreads();                              // drains vmcnt(0)

    #pragma unroll
    for (int kt = 0; kt < 4; ++kt) {              // K-stages of 64
        const int buf = kt & 1;
        if (kt < 3) STAGE(buf ^ 1, kt + 1);       // issue BEFORE compute
        #pragma unroll
        for (int ks = 0; ks < 2; ++ks) {          // 2 k-steps of 32 per stage
            const int cq = (ks * 4 + lq) ^ (lr & 7);
            bf16x8 fa[4];
            #pragma unroll
            for (int fm = 0; fm < 4; ++fm) {
                int ra = wr * 64 + fm * 16 + lr;
                fa[fm] = *(const bf16x8*)((const char*)&lsA[buf][0] + ra * 128 + cq * 16);
            }
            #pragma unroll
            for (int fn = 0; fn < 2; ++fn) {
                int rb = wc * 32 + fn * 16 + lr;
                bf16x8 fbv = *(const bf16x8*)((const char*)&lsB[buf][0] + rb * 128 + cq * 16);
                #pragma unroll
                for (int fm = 0; fm < 4; ++fm)
                    acc[fm][fn] = __builtin_amdgcn_mfma_f32_16x16x32_bf16(
                        fa[fm], fbv, acc[fm][fn], 0, 0, 0);
            }
        }
        __syncthreads();   // drain: next-buf loads had the whole compute to fly
    }
#undef STAGE

    // ---- fused epilogue: unified softplus in log2 units (validated) ----
    const int mcol = tj * 4 + wc;                // this wave's 32-col mask word
    const bool dtile = (ti == tj);
    float tsum = 0.0f;
    #pragma unroll
    for (int fm = 0; fm < 4; ++fm) {
        #pragma unroll
        for (int r2 = 0; r2 < 4; ++r2) {
            int rl   = wr * 64 + fm * 16 + lq * 4 + r2;       // local row
            unsigned mw = g_mask[(size_t)(ti * 128 + rl) * (NN/32) + mcol];
            #pragma unroll
            for (int fn = 0; fn < 2; ++fn) {
                float s = acc[fm][fn][r2];
                int cl  = wc * 32 + fn * 16 + lr;             // local col
                bool bit = ((mw >> (fn * 16 + lr)) & 1) != 0;
                float wv = s * L2E;
                float aw = bit ? -wv : wv;
                float e2 = __builtin_amdgcn_exp2f(aw);
                float l  = __builtin_amdgcn_logf(1.0f + e2);  // log2(1+2^aw)
                float thr = bit ? 128.0f : 24.0f;
                float term = (aw >= thr) ? SAT_L2 : l;
                if (dtile && rl == cl)
                    term = bit ? SAT_L2 : 0.0f;               // masked diagonal
                tsum += term;
            }
        }
    }
    // wave reduce -> LDS -> one plain f64 store per block (no contended atomics)
    #pragma unroll
    for (int off = 32; off; off >>= 1) tsum += __shfl_down(tsum, off);
    if (lane == 0) s_part[w] = (double)tsum;
    __syncthreads();
    if (tid == 0) {
        double acc8 = ((s_part[0] + s_part[1]) + (s_part[2] + s_part[3]))
                    + ((s_part[4] + s_part[5]) + (s_part[6] + s_part[7]));
        double wgt = (ti == tj) ? LN2D : 2.0 * LN2D;          // fold ln2 here
        g_part[orig] = acc8 * wgt;
    }
}

// ---- Kernel 3: final reduce (block 0) + mask cleanup (all 512 blocks) ----
__global__ void k_final(const long long* __restrict__ ei, float* __restrict__ out) {
    int e = blockIdx.x * 256 + threadIdx.x;
    if (e < NE) {
        int ii = (int)ei[e];
        int jj = (int)ei[NE + e];
        g_mask[(size_t)ii * (NN/32) + (jj >> 5)] = 0u;
        g_mask[(size_t)jj * (NN/32) + (ii >> 5)] = 0u;
    }
    if (blockIdx.x == 0) {
        __shared__ double sd[256];
        double s = 0.0;
        for (int i = threadIdx.x; i < NBLK; i += 256) s += g_part[i];
        sd[threadIdx.x] = s;
        __syncthreads();
        #pragma unroll
        for (int st = 128; st; st >>= 1) {
            if (threadIdx.x < st) sd[threadIdx.x] += sd[threadIdx.x + st];
            __syncthreads();
        }
        if (threadIdx.x == 0)
            out[0] = (float)(sd[0] * (1.0 / ((double)NN * (double)NN)));
    }
}

extern "C" void kernel_launch(void* const* d_in, const int* in_sizes, int n_in,
                              void* d_out, int out_size, void* d_ws, size_t ws_size,
                              hipStream_t stream) {
    const float* l_enc = (const float*)d_in[0];
    const long long* ei = (const long long*)d_in[1];
    float* out = (float*)d_out;

    k_convscat<<<2048, 256, 0, stream>>>(l_enc, ei);
    k_loss<<<NBLK, 512, 0, stream>>>();
    k_final<<<NE / 256, 256, 0, stream>>>(ei, out);
}

// Round 19
// 57.987 us; speedup vs baseline: 1.1062x; 1.1062x over previous
//
#include <hip/hip_runtime.h>
#include <hip/hip_bf16.h>

#define NN 8192
#define DK 256
#define NE 131072
#define T128 64                       // 128-row tiles per dim
#define NBLK (T128*(T128+1)/2)        // 2080 upper-triangular tile pairs
#define L2E 1.44269504f
#define SAT_L2 144.269504f            // 100/ln2 (x ln2 at block scale -> 100)
#define LN2D 0.6931471805599453

typedef __attribute__((ext_vector_type(8))) short bf16x8;
typedef __attribute__((ext_vector_type(4))) float f32x4;
typedef const __attribute__((address_space(1))) void* gas1_t;
typedef __attribute__((address_space(3))) void* las3_t;

// g_mask: BSS-zero at load; scatter sets bits, k_final's edge-cleanup
// (plain stores of 0) restores all-zero every call. No zeroing pass.
__device__ __align__(16) unsigned       g_mask[(size_t)NN*NN/32]; // 8 MB bitmask
__device__ __align__(16) unsigned short g_bf[(size_t)NN*DK];      // 4 MB bf16 copy
__device__ __align__(16) double g_part[NBLK];                     // per-block partials

__device__ __forceinline__ unsigned short f2bf(float f) {
    unsigned u = __float_as_uint(f);
    unsigned r = (u + 0x7FFFu + ((u >> 16) & 1u)) >> 16;   // RNE
    return (unsigned short)r;
}

// ---- Kernel 1: convert l_enc->bf16 AND scatter edges ----
__global__ void k_convscat(const float* __restrict__ x,
                           const long long* __restrict__ ei) {
    int i = blockIdx.x * 256 + threadIdx.x;          // 0 .. 524287
    float4 v = ((const float4*)x)[i];
    ushort4 b;
    b.x = f2bf(v.x); b.y = f2bf(v.y); b.z = f2bf(v.z); b.w = f2bf(v.w);
    *(ushort4*)(&g_bf[(size_t)i * 4]) = b;
    if (blockIdx.x < NE / 256) {                     // first 512 blocks: 256 edges each
        int e = blockIdx.x * 256 + threadIdx.x;
        int ii = (int)ei[e];
        int jj = (int)ei[NE + e];
        atomicOr(&g_mask[(size_t)ii * (NN/32) + (jj >> 5)], 1u << (jj & 31));
        atomicOr(&g_mask[(size_t)jj * (NN/32) + (ii >> 5)], 1u << (ii & 31));
    }
}

// ---- Kernel 2: single-buffer async-staged gram + fused BCE reduction ----
// R14 structure — empirical optimum of 9 measured variants (k_loss ~38.5us):
// BK=64, 32 KB LDS, (256,3) no-spill, 2 barriers/stage, 3 blocks/CU.
// Falsified alternatives: (256,4)/(512,4) reg caps spill or add LDS traffic
// (R7/R8/R18), BK=32 dbuf halves the latency-cover window (R12), mask
// prefetch + reader-zeroing dirty L2 (R16), completion ticket serializes
// (R10). Epilogue: softplus in log2 units (absmax 0.0 across R15-R18):
// term_l2 = log2(1+2^aw), aw = bit ? -wv : wv, wv = s*log2e; override
// SAT_L2 when aw >= (bit ? 128 : 24) — ref's fp32 expf-overflow and
// fl(1+e)==1 saturation boundaries. ln2 folded into per-block weight.
__global__ __launch_bounds__(256, 3) void k_loss() {
    __shared__ __align__(16) unsigned short lsA[128 * 64];   // 16 KB
    __shared__ __align__(16) unsigned short lsB[128 * 64];   // 16 KB
    __shared__ double s_part[4];

    // XCD-aware swizzle (2080 = 8*260, bijective), then decode (ti,tj), ti<=tj
    int orig = blockIdx.x;
    int bid  = (orig & 7) * (NBLK / 8) + (orig >> 3);
    int rem = bid, ti = 0;
    while (rem >= T128 - ti) { rem -= T128 - ti; ++ti; }
    int tj = ti + rem;

    const int tid  = threadIdx.x;
    const int lane = tid & 63;
    const int w    = tid >> 6;       // wave 0..3
    const int wr   = w >> 1;         // wave row 0..1
    const int wc   = w & 1;          // wave col 0..1
    const int lr   = lane & 15;
    const int lq   = lane >> 4;      // 0..3

    // staging: LDS chunk c=(r,sq) holds global chunk (r, sq^(r&7)).
    const int gq = (tid & 7) ^ ((tid >> 3) & 7);
    const unsigned short* srcA0 = g_bf + (size_t)(ti * 128 + (tid >> 3)) * DK + gq * 8;
    const size_t dB = (size_t)(tj - ti) * 128 * DK;   // B-panel offset (uniform)
    const int lds0 = tid * 8;                          // element offset, 16 B/lane

#define STAGE(kt) do {                                                             \
    _Pragma("unroll")                                                              \
    for (int i = 0; i < 4; ++i) {                                                  \
        __builtin_amdgcn_global_load_lds(                                          \
            (gas1_t)(const void*)(srcA0 + (size_t)i * 32 * DK + (kt) * 64),        \
            (las3_t)(void*)&lsA[lds0 + i * 2048], 16, 0, 0);                       \
        __builtin_amdgcn_global_load_lds(                                          \
            (gas1_t)(const void*)(srcA0 + dB + (size_t)i * 32 * DK + (kt) * 64),   \
            (las3_t)(void*)&lsB[lds0 + i * 2048], 16, 0, 0);                       \
    }                                                                              \
} while (0)

    f32x4 acc[4][4] = {};

    // prologue: stage kt=0
    STAGE(0);
    __syncthreads();                              // drains vmcnt(0)

    #pragma unroll
    for (int kt = 0; kt < 4; ++kt) {              // K-stages of 64
        #pragma unroll
        for (int ks = 0; ks < 2; ++ks) {          // 2 k-steps of 32 per stage
            const int cq = (ks * 4 + lq) ^ (lr & 7);
            bf16x8 fa[4];
            #pragma unroll
            for (int fm = 0; fm < 4; ++fm) {
                int ra = wr * 64 + fm * 16 + lr;
                fa[fm] = *(const bf16x8*)((const char*)&lsA[0] + ra * 128 + cq * 16);
            }
            #pragma unroll
            for (int fn = 0; fn < 4; ++fn) {
                int rb = wc * 64 + fn * 16 + lr;
                bf16x8 fbv = *(const bf16x8*)((const char*)&lsB[0] + rb * 128 + cq * 16);
                #pragma unroll
                for (int fm = 0; fm < 4; ++fm)
                    acc[fm][fn] = __builtin_amdgcn_mfma_f32_16x16x32_bf16(
                        fa[fm], fbv, acc[fm][fn], 0, 0, 0);
            }
        }
        if (kt < 3) {
            __syncthreads();                      // all waves done reading LDS
            STAGE(kt + 1);
            __syncthreads();                      // staging drained (vmcnt(0)+barrier)
        }
    }
#undef STAGE

    // ---- fused epilogue: unified softplus in log2 units ----
    const int R0 = ti * 128 + wr * 64;
    const int C0 = tj * 128 + wc * 64;           // 64-aligned
    const char* mrow0 = (const char*)g_mask + (size_t)(C0 >> 5) * 4;
    const bool diagB = (ti == tj) && (wr == wc);
    float tsum = 0.0f;
    #pragma unroll
    for (int fm = 0; fm < 4; ++fm) {
        #pragma unroll
        for (int r2 = 0; r2 < 4; ++r2) {
            int rowg = R0 + fm * 16 + lq * 4 + r2;
            uint2 m2 = *(const uint2*)(mrow0 + (size_t)rowg * (NN / 8));  // in-loop load
            #pragma unroll
            for (int fn = 0; fn < 4; ++fn) {
                float s = acc[fm][fn][r2];
                unsigned mw = (fn & 2) ? m2.y : m2.x;
                bool bit = ((mw >> ((fn & 1) * 16 + lr)) & 1) != 0;
                float wv = s * L2E;
                float aw = bit ? -wv : wv;
                float e2 = __builtin_amdgcn_exp2f(aw);
                float l  = __builtin_amdgcn_logf(1.0f + e2);   // log2(1+2^aw)
                float thr = bit ? 128.0f : 24.0f;
                float term = (aw >= thr) ? SAT_L2 : l;         // select covers inf path
                if (diagB && fm == fn && (lq * 4 + r2) == lr)
                    term = bit ? SAT_L2 : 0.0f;                // masked diagonal
                tsum += term;
            }
        }
    }
    // wave reduce -> LDS -> one plain f64 store per block (no contended atomics)
    #pragma unroll
    for (int off = 32; off; off >>= 1) tsum += __shfl_down(tsum, off);
    if (lane == 0) s_part[w] = (double)tsum;
    __syncthreads();
    if (tid == 0) {
        double wgt = (ti == tj) ? LN2D : 2.0 * LN2D;           // fold ln2 here
        g_part[orig] = ((s_part[0] + s_part[1]) + (s_part[2] + s_part[3])) * wgt;
    }
}

// ---- Kernel 3: final reduce (block 0) + mask cleanup (all 512 blocks) ----
// Cleanup restores g_mask to all-zero by plain-storing 0 to exactly the
// words the scatter touched (duplicate writes race benignly: all write 0).
__global__ void k_final(const long long* __restrict__ ei, float* __restrict__ out) {
    int e = blockIdx.x * 256 + threadIdx.x;
    if (e < NE) {
        int ii = (int)ei[e];
        int jj = (int)ei[NE + e];
        g_mask[(size_t)ii * (NN/32) + (jj >> 5)] = 0u;
        g_mask[(size_t)jj * (NN/32) + (ii >> 5)] = 0u;
    }
    if (blockIdx.x == 0) {
        __shared__ double sd[256];
        double s = 0.0;
        for (int i = threadIdx.x; i < NBLK; i += 256) s += g_part[i];
        sd[threadIdx.x] = s;
        __syncthreads();
        #pragma unroll
        for (int st = 128; st; st >>= 1) {
            if (threadIdx.x < st) sd[threadIdx.x] += sd[threadIdx.x + st];
            __syncthreads();
        }
        if (threadIdx.x == 0)
            out[0] = (float)(sd[0] * (1.0 / ((double)NN * (double)NN)));
    }
}

extern "C" void kernel_launch(void* const* d_in, const int* in_sizes, int n_in,
                              void* d_out, int out_size, void* d_ws, size_t ws_size,
                              hipStream_t stream) {
    const float* l_enc = (const float*)d_in[0];
    const long long* ei = (const long long*)d_in[1];
    float* out = (float*)d_out;

    k_convscat<<<2048, 256, 0, stream>>>(l_enc, ei);
    k_loss<<<NBLK, 256, 0, stream>>>();
    k_final<<<NE / 256, 256, 0, stream>>>(ei, out);
}